// Round 12
// baseline (384.701 us; speedup 1.0000x reference)
//
#include <hip/hip_runtime.h>
#include <hip/hip_fp16.h>
#include <math.h>

#define L 4096
#define CDIM 256
#define DIN 512
#define DSTATE 16
#define DTR 16
#define BATCH 4

using f32x4  = __attribute__((ext_vector_type(4))) float;
using f16x8  = __attribute__((ext_vector_type(8))) _Float16;

__device__ __forceinline__ float silu_f(float x) { return x / (1.f + __expf(-x)); }
__device__ __forceinline__ float softplus_fast(float x) {
    return (x > 20.f) ? x : __logf(1.f + __expf(x));
}
// two fp32 -> one u32 holding two rn fp16
__device__ __forceinline__ unsigned pk2h(float a, float b) {
    __half2 h = __floats2half2_rn(a, b);
    return *reinterpret_cast<unsigned*>(&h);
}

#define LDK 40

// ================= single-plane fp16 MFMA GEMM =================
// Out[b,m,n] = sum_k A*W. A fp16 row-major (or fp32 K-major for GEMM1).
// Block 128 x (2*NT*16); waves 2x2; wave tile (MT*16)x(NT*16). fp32 accumulate.
enum { HEPI_XP = 0, HEPI_UZ = 1, HEPI_F32 = 2, HEPI_D34 = 3 };
template<int EPI, bool A_F32KM, int MT, int NT>
__global__ __launch_bounds__(256)
void hgemm(const float* __restrict__ Af0, const float* __restrict__ Af1,
           const __half* __restrict__ Ah_g, const __half* __restrict__ Bh_g,
           const float* __restrict__ bias,
           float* __restrict__ O0, __half* __restrict__ Oh0, __half* __restrict__ Oh1,
           float* __restrict__ Ob, float* __restrict__ Oc,
           int M, int N, int K, int kSplit, long strideAb, int nBlk)
{
    constexpr int BN = 2 * NT * 16;
    constexpr int BSEG = BN / 64;
    __shared__ __align__(16) _Float16 Ah[128][LDK];
    __shared__ __align__(16) _Float16 Bh[BN][LDK];
    const int mBlk = M / 128;
    // XCD-sticky swizzle: n-blocks of one (b,m) A-tile share bid%8 -> same XCD L2
    const int bid = blockIdx.x;
    const int r = bid & 7, q = bid >> 3;
    const int ni = q % nBlk;
    const int mg = (q / nBlk) * 8 + r;
    const int b = mg / mBlk, m_idx = mg - b * mBlk;
    const int n0 = ni * BN, m0 = m_idx * 128;
    const int tid  = threadIdx.x;
    const int lane = tid & 63;
    const int w    = tid >> 6;
    const int wr   = w >> 1, wc = w & 1;
    const int lrow = lane & 15;
    const int loct = lane >> 4;

    f32x4 acc[MT][NT];
    #pragma unroll
    for (int i = 0; i < MT; ++i)
        #pragma unroll
        for (int j = 0; j < NT; ++j)
            acc[i][j] = (f32x4){0.f, 0.f, 0.f, 0.f};

    const int sOct = tid & 3, sRow = tid >> 2;
    float va[16];
    uint4 pa[2], pb[BSEG];

    auto loadA = [&](int kk) {
        if (A_F32KM) {
            int m = tid & 127, half = tid >> 7;
            #pragma unroll
            for (int j = 0; j < 16; ++j) {
                int kg = kk + half * 16 + j;
                const float* Ap; int kl;
                if (kg < kSplit) { Ap = Af0; kl = kg; } else { Ap = Af1; kl = kg - kSplit; }
                va[j] = Ap[(long)b * strideAb + (long)kl * M + m0 + m];
            }
        } else {
            #pragma unroll
            for (int p = 0; p < 2; ++p)
                pa[p] = *(const uint4*)(Ah_g + (long)b * strideAb +
                                        (long)(m0 + sRow + p * 64) * K + kk + sOct * 8);
        }
    };
    auto loadB = [&](int kk) {
        #pragma unroll
        for (int p = 0; p < BSEG; ++p) {
            int ng = n0 + sRow + p * 64;
            if (EPI == HEPI_D34 && ng >= N)
                pb[p] = make_uint4(0, 0, 0, 0);
            else
                pb[p] = *(const uint4*)(Bh_g + (long)ng * K + kk + sOct * 8);
        }
    };
    auto storeAB = [&]() {
        if (A_F32KM) {
            int m = tid & 127, half = tid >> 7;
            #pragma unroll
            for (int o = 0; o < 2; ++o) {
                uint4 h;
                h.x = pk2h(va[o*8+0], va[o*8+1]);
                h.y = pk2h(va[o*8+2], va[o*8+3]);
                h.z = pk2h(va[o*8+4], va[o*8+5]);
                h.w = pk2h(va[o*8+6], va[o*8+7]);
                *(uint4*)&Ah[m][half*16 + o*8] = h;
            }
        } else {
            #pragma unroll
            for (int p = 0; p < 2; ++p)
                *(uint4*)&Ah[sRow + p*64][sOct*8] = pa[p];
        }
        #pragma unroll
        for (int p = 0; p < BSEG; ++p)
            *(uint4*)&Bh[sRow + p*64][sOct*8] = pb[p];
    };

    loadA(0); loadB(0);
    for (int kk = 0; kk < K; kk += 32) {
        storeAB();
        __syncthreads();
        if (kk + 32 < K) { loadA(kk + 32); loadB(kk + 32); }   // in flight during MFMA
        f16x8 bh[NT];
        #pragma unroll
        for (int nt = 0; nt < NT; ++nt)
            bh[nt] = *(const f16x8*)&Bh[wc*NT*16 + nt*16 + lrow][loct*8];
        #pragma unroll
        for (int mt = 0; mt < MT; ++mt) {
            f16x8 ah = *(const f16x8*)&Ah[wr*MT*16 + mt*16 + lrow][loct*8];
            #pragma unroll
            for (int nt = 0; nt < NT; ++nt)
                acc[mt][nt] = __builtin_amdgcn_mfma_f32_16x16x32_f16(ah, bh[nt], acc[mt][nt], 0, 0, 0);
        }
        __syncthreads();
    }
    // epilogue: C/D col=lane&15, row=(lane>>4)*4+reg
    #pragma unroll
    for (int mt = 0; mt < MT; ++mt) {
        #pragma unroll
        for (int r4 = 0; r4 < 4; ++r4) {
            int m = m0 + wr*MT*16 + mt * 16 + loct * 4 + r4;
            long rowb = (long)b * M + m;
            #pragma unroll
            for (int nt = 0; nt < NT; ++nt) {
                int n = n0 + wc*NT*16 + nt * 16 + lrow;
                float v = acc[mt][nt][r4];
                if (EPI == HEPI_XP) {
                    Oh0[rowb * N + n] = __float2half(v + bias[n]);
                } else if (EPI == HEPI_UZ) {
                    if (n < DIN) Oh0[rowb * DIN + n] = __float2half(v);
                    else         Oh1[rowb * DIN + (n - DIN)] = __float2half(v);
                } else if (EPI == HEPI_D34) {
                    if (n < DIN)            O0[rowb * DIN + n] = softplus_fast(v + bias[n]);
                    else if (n < DIN + 16)  Ob[rowb * 16 + (n - DIN)] = v;
                    else if (n < DIN + 32)  Oc[rowb * 16 + (n - DIN - 16)] = v;
                } else {
                    O0[rowb * N + n] = v;
                }
            }
        }
    }
}

// ---------------- merged weight prep: all weights -> fp16 (Wcomb fused product) ----
#define SZ_WP  131072
#define SZ_WIN 262144
#define SZ_WO  131072
#define SZ_WC  278528
__global__ __launch_bounds__(256)
void pack_all(const float* __restrict__ Wp, const float* __restrict__ Win,
              const float* __restrict__ Wout, const float* __restrict__ Wdt,
              const float* __restrict__ Wx,
              __half* __restrict__ wph, __half* __restrict__ winh,
              __half* __restrict__ woh, __half* __restrict__ wch)
{
    int i = blockIdx.x * 256 + threadIdx.x;
    if (i < SZ_WP) { wph[i] = __float2half(Wp[i]); return; }
    i -= SZ_WP;
    if (i < SZ_WIN) { winh[i] = __float2half(Win[i]); return; }
    i -= SZ_WIN;
    if (i < SZ_WO) { woh[i] = __float2half(Wout[i]); return; }
    i -= SZ_WO;
    if (i < SZ_WC) {
        int n = i >> 9, k = i & 511;
        float acc;
        if (n < DIN) {
            acc = 0.f;
            #pragma unroll
            for (int rr = 0; rr < DTR; ++rr)
                acc += Wdt[n * DTR + rr] * Wx[rr * DIN + k];
        } else {
            acc = Wx[(DTR + (n - DIN)) * DIN + k];
        }
        wch[i] = __float2half(acc);
    }
}

// ---------------- depthwise causal conv (k=4) + silu: fp16 in -> fp16 out ---------
__global__ __launch_bounds__(256)
void conv_silu_kernel(const __half* __restrict__ u_pre, const float* __restrict__ cw,
                      const float* __restrict__ cb, __half* __restrict__ u)
{
    long idx = (long)blockIdx.x * blockDim.x + threadIdx.x;
    int d = (int)(idx % DIN);
    long bl = idx / DIN;
    int l = (int)(bl % L);
    long brow = bl - l;
    float v = cb[d];
    #pragma unroll
    for (int j = 0; j < 4; ++j) {
        int li = l - 3 + j;
        if (li >= 0) v += __half2float(u_pre[(brow + li) * DIN + d]) * cw[d * 4 + j];
    }
    u[idx] = __float2half(silu_f(v));
}

// ---------------- chunked parallel selective scan, d-per-lane ----------------
#define NC 128
#define LC (L / NC)

__global__ __launch_bounds__(256)
void scan_phase1(const float* __restrict__ delta, const __half* __restrict__ u,
                 const float* __restrict__ Bm, const float* __restrict__ A_log,
                 float* __restrict__ Asum, float* __restrict__ Xsum)
{
    __shared__ float sB[LC][DSTATE];
    const int gd = blockIdx.x & 1;
    const int c  = (blockIdx.x >> 1) & (NC - 1);
    const int b  = blockIdx.x >> 8;
    const int d  = gd * 256 + threadIdx.x;
    const int t0 = c * LC;
    float Arow[DSTATE];
    #pragma unroll
    for (int q = 0; q < 4; ++q) {
        float4 v = *(const float4*)&A_log[d * DSTATE + q * 4];
        Arow[q * 4 + 0] = -__expf(v.x);
        Arow[q * 4 + 1] = -__expf(v.y);
        Arow[q * 4 + 2] = -__expf(v.z);
        Arow[q * 4 + 3] = -__expf(v.w);
    }
    for (int i = threadIdx.x; i < LC * DSTATE; i += 256)
        sB[i >> 4][i & 15] = Bm[((long)b * L + t0 + (i >> 4)) * DSTATE + (i & 15)];
    __syncthreads();
    float P[DSTATE], X[DSTATE];
    #pragma unroll
    for (int s = 0; s < DSTATE; ++s) { P[s] = 1.f; X[s] = 0.f; }
    for (int t = 0; t < LC; ++t) {
        long gidx = ((long)b * L + t0 + t) * DIN + d;
        float dlt = delta[gidx];
        float du  = dlt * __half2float(u[gidx]);
        #pragma unroll
        for (int s = 0; s < DSTATE; ++s) {
            float a = __expf(dlt * Arow[s]);
            P[s] *= a;
            X[s] = a * X[s] + du * sB[t][s];
        }
    }
    long o = (((long)b * NC + c) * DIN + d) * DSTATE;
    #pragma unroll
    for (int q = 0; q < 4; ++q) {
        *(float4*)&Asum[o + q * 4] = make_float4(P[q*4], P[q*4+1], P[q*4+2], P[q*4+3]);
        *(float4*)&Xsum[o + q * 4] = make_float4(X[q*4], X[q*4+1], X[q*4+2], X[q*4+3]);
    }
}

__global__ __launch_bounds__(256)
void scan_phase2(const float* __restrict__ Asum, float* __restrict__ Xsum)
{
    int lane = blockIdx.x * 256 + threadIdx.x;
    int b = lane / (DIN * DSTATE);
    int rem = lane % (DIN * DSTATE);
    float h = 0.f;
    for (int c = 0; c < NC; ++c) {
        long idx = ((long)b * NC + c) * (DIN * DSTATE) + rem;
        float A = Asum[idx], X = Xsum[idx];
        Xsum[idx] = h;
        h = A * h + X;
    }
}

__global__ __launch_bounds__(256)
void scan_phase3(const float* __restrict__ delta, const __half* __restrict__ u,
                 const float* __restrict__ Bm, const float* __restrict__ Cm,
                 const __half* __restrict__ z, const float* __restrict__ A_log,
                 const float* __restrict__ Dp, const float* __restrict__ Hinit,
                 __half* __restrict__ y2h)
{
    __shared__ float sB[LC][DSTATE], sC[LC][DSTATE];
    const int gd = blockIdx.x & 1;
    const int c  = (blockIdx.x >> 1) & (NC - 1);
    const int b  = blockIdx.x >> 8;
    const int d  = gd * 256 + threadIdx.x;
    const int t0 = c * LC;
    float Arow[DSTATE];
    #pragma unroll
    for (int q = 0; q < 4; ++q) {
        float4 v = *(const float4*)&A_log[d * DSTATE + q * 4];
        Arow[q * 4 + 0] = -__expf(v.x);
        Arow[q * 4 + 1] = -__expf(v.y);
        Arow[q * 4 + 2] = -__expf(v.z);
        Arow[q * 4 + 3] = -__expf(v.w);
    }
    for (int i = threadIdx.x; i < LC * DSTATE; i += 256) {
        long gidx = ((long)b * L + t0 + (i >> 4)) * DSTATE + (i & 15);
        sB[i >> 4][i & 15] = Bm[gidx];
        sC[i >> 4][i & 15] = Cm[gidx];
    }
    float h[DSTATE];
    {
        long o = (((long)b * NC + c) * DIN + d) * DSTATE;
        #pragma unroll
        for (int q = 0; q < 4; ++q) {
            float4 v = *(const float4*)&Hinit[o + q * 4];
            h[q * 4 + 0] = v.x; h[q * 4 + 1] = v.y;
            h[q * 4 + 2] = v.z; h[q * 4 + 3] = v.w;
        }
    }
    const float Dval = Dp[d];
    __syncthreads();
    for (int t = 0; t < LC; ++t) {
        long gidx = ((long)b * L + t0 + t) * DIN + d;
        float dlt = delta[gidx];
        float uu  = __half2float(u[gidx]);
        float zz  = __half2float(z[gidx]);
        float du  = dlt * uu;
        float y = 0.f;
        #pragma unroll
        for (int s = 0; s < DSTATE; ++s) {
            float a = __expf(dlt * Arow[s]);
            h[s] = h[s] * a + du * sB[t][s];
            y += h[s] * sC[t][s];
        }
        y2h[gidx] = __float2half((y + uu * Dval) * silu_f(zz));
    }
}

// ---------------- LayerNorm over C + transpose to (B,C,L) ----------------
__global__ __launch_bounds__(256)
void ln_kernel(const float* __restrict__ X, const float* __restrict__ gamma,
               const float* __restrict__ beta, float* __restrict__ out)
{
    __shared__ float tile[32][257];
    __shared__ float sMu[32], sRs[32];
    const int l0 = blockIdx.x * 32;
    const int b  = blockIdx.y;
    const int tid = threadIdx.x;
    for (int i = tid; i < 32 * 256; i += 256) {
        int l = i >> 8, c = i & 255;
        tile[l][c] = X[((long)b * L + l0 + l) * CDIM + c];
    }
    __syncthreads();
    {
        int l = tid >> 3, sub = tid & 7;
        float s1 = 0.f, s2 = 0.f;
        for (int c = sub * 32; c < sub * 32 + 32; ++c) {
            float v = tile[l][c];
            s1 += v; s2 += v * v;
        }
        s1 += __shfl_xor(s1, 1); s2 += __shfl_xor(s2, 1);
        s1 += __shfl_xor(s1, 2); s2 += __shfl_xor(s2, 2);
        s1 += __shfl_xor(s1, 4); s2 += __shfl_xor(s2, 4);
        if (sub == 0) {
            float mu = s1 * (1.f / 256.f);
            float var = s2 * (1.f / 256.f) - mu * mu;
            sMu[l] = mu;
            sRs[l] = rsqrtf(var + 1e-5f);
        }
    }
    __syncthreads();
    for (int i = tid; i < 32 * 256; i += 256) {
        int ll = i & 31, c = i >> 5;
        float v = (tile[ll][c] - sMu[ll]) * sRs[ll] * gamma[c] + beta[c];
        out[((long)b * CDIM + c) * L + l0 + ll] = v;
    }
}

extern "C" void kernel_launch(void* const* d_in, const int* in_sizes, int n_in,
                              void* d_out, int out_size, void* d_ws, size_t ws_size,
                              hipStream_t stream)
{
    const float* sp   = (const float*)d_in[0];
    const float* fq   = (const float*)d_in[1];
    const float* Wp   = (const float*)d_in[2];
    const float* bp   = (const float*)d_in[3];
    const float* Win  = (const float*)d_in[4];
    const float* cw   = (const float*)d_in[5];
    const float* cb   = (const float*)d_in[6];
    const float* Wx   = (const float*)d_in[7];
    const float* Wdt  = (const float*)d_in[8];
    const float* bdt  = (const float*)d_in[9];
    const float* Alog = (const float*)d_in[10];
    const float* Dp   = (const float*)d_in[11];
    const float* Wout = (const float*)d_in[12];
    const float* gam  = (const float*)d_in[13];
    const float* bet  = (const float*)d_in[14];
    float* out = (float*)d_out;
    float* ws  = (float*)d_ws;

    const size_t NLD = (size_t)BATCH * L * DIN;   // 8.39M
    const size_t NLC = (size_t)BATCH * L * CDIM;  // 4.19M

    size_t off = 0;
    float*  delta = ws + off; off += NLD;                 // fp32 delta
    __half* u16   = (__half*)(ws + off); off += NLD / 2;  // pre-conv u
    __half* u16c  = (__half*)(ws + off); off += NLD / 2;  // post-conv silu(u)
    __half* z16   = (__half*)(ws + off); off += NLD / 2;
    __half* y16   = (__half*)(ws + off); off += NLD / 2;
    __half* xp16  = (__half*)(ws + off); off += NLC / 2;
    float*  xmix  = ws + off; off += NLC;
    __half* wph   = (__half*)(ws + off); off += SZ_WP / 2;
    __half* winh  = (__half*)(ws + off); off += SZ_WIN / 2;
    __half* woh   = (__half*)(ws + off); off += SZ_WO / 2;
    __half* wch   = (__half*)(ws + off); off += SZ_WC / 2;
    float*  Bmb   = ws + off; off += (size_t)BATCH * L * DSTATE;
    float*  Cmb   = ws + off; off += (size_t)BATCH * L * DSTATE;
    float*  Asum  = ws + off; off += (size_t)BATCH * NC * DIN * DSTATE;
    float*  Xsum  = ws + off; off += (size_t)BATCH * NC * DIN * DSTATE;

    dim3 blk(256);
    pack_all<<<dim3((SZ_WP + SZ_WIN + SZ_WO + SZ_WC) / 256), blk, 0, stream>>>(
        Wp, Win, Wout, Wdt, Wx, wph, winh, woh, wch);

    // GEMM1 (fp16): x_proj = x_cat @ Wp^T + bp  (A fp32 K-major; MT=4,NT=2, nBlk=4)
    hgemm<HEPI_XP, true, 4, 2><<<dim3(BATCH * (L/128) * 4), blk, 0, stream>>>(
        sp, fq, nullptr, wph, bp, nullptr, xp16, nullptr, nullptr, nullptr,
        L, CDIM, 2 * CDIM, CDIM, (long)CDIM * L, 4);
    // GEMM2 (fp16): xz = x_proj @ Win^T -> u16 / z16  (MT=4,NT=4, nBlk=8)
    hgemm<HEPI_UZ, false, 4, 4><<<dim3(BATCH * (L/128) * 8), blk, 0, stream>>>(
        nullptr, nullptr, xp16, winh, nullptr, nullptr, u16, z16, nullptr, nullptr,
        L, 2 * DIN, CDIM, 1 << 30, (long)L * CDIM, 8);
    conv_silu_kernel<<<dim3((int)(NLD / 256)), blk, 0, stream>>>(u16, cw, cb, u16c);
    // D34 (fp16): [delta | Bm | Cm] = u @ Wcomb^T, softplus on delta (MT=4,NT=4, nBlk=5)
    hgemm<HEPI_D34, false, 4, 4><<<dim3(BATCH * (L/128) * 5), blk, 0, stream>>>(
        nullptr, nullptr, u16c, wch, bdt, delta, nullptr, nullptr, Bmb, Cmb,
        L, 544, DIN, 1 << 30, (long)L * DIN, 5);

    scan_phase1<<<dim3(BATCH * NC * 2), blk, 0, stream>>>(delta, u16c, Bmb, Alog, Asum, Xsum);
    scan_phase2<<<dim3(BATCH * DIN * DSTATE / 256), blk, 0, stream>>>(Asum, Xsum);
    scan_phase3<<<dim3(BATCH * NC * 2), blk, 0, stream>>>(
        delta, u16c, Bmb, Cmb, z16, Alog, Dp, Xsum, y16);

    // GEMM5 (fp16): x_mixed = y2 @ Wout^T  (MT=4,NT=2, nBlk=4)
    hgemm<HEPI_F32, false, 4, 2><<<dim3(BATCH * (L/128) * 4), blk, 0, stream>>>(
        nullptr, nullptr, y16, woh, nullptr, xmix, nullptr, nullptr, nullptr, nullptr,
        L, CDIM, DIN, 1 << 30, (long)L * DIN, 4);
    ln_kernel<<<dim3(L / 32, BATCH), blk, 0, stream>>>(xmix, gam, bet, out);
}

// Round 13
// 363.712 us; speedup vs baseline: 1.0577x; 1.0577x over previous
//
#include <hip/hip_runtime.h>
#include <hip/hip_fp16.h>
#include <math.h>

#define L 4096
#define CDIM 256
#define DIN 512
#define DSTATE 16
#define DTR 16
#define BATCH 4

using f32x4  = __attribute__((ext_vector_type(4))) float;
using f16x8  = __attribute__((ext_vector_type(8))) _Float16;

__device__ __forceinline__ float silu_f(float x) { return x / (1.f + __expf(-x)); }
__device__ __forceinline__ float softplus_fast(float x) {
    return (x > 20.f) ? x : __logf(1.f + __expf(x));
}
__device__ __forceinline__ unsigned pk2h(float a, float b) {
    __half2 h = __floats2half2_rn(a, b);
    return *reinterpret_cast<unsigned*>(&h);
}

#define LDK 40

// ================= fp16 MFMA GEMM: 64-row tiles, double-buffered single-barrier ====
// Out[b,m,n] = sum_k A*W. A fp16 row-major (or fp32 K-major for GEMM1).
// Block 64 x (2*NT*16); 4 waves 2x2; wave tile 32 x (NT*16). fp32 accumulate.
// k-loop: load(kk+32) -> mfma buf[cur] -> store buf[cur^1] -> ONE barrier.
enum { HEPI_XP = 0, HEPI_UZ = 1, HEPI_F32 = 2, HEPI_D34 = 3 };
template<int EPI, bool A_F32KM, int NT>
__global__ __launch_bounds__(256)
void hgemm(const float* __restrict__ Af0, const float* __restrict__ Af1,
           const __half* __restrict__ Ah_g, const __half* __restrict__ Bh_g,
           const float* __restrict__ bias,
           float* __restrict__ O0, __half* __restrict__ Oh0, __half* __restrict__ Oh1,
           float* __restrict__ Ob, float* __restrict__ Oc,
           int M, int N, int K, int kSplit, long strideAb, int nBlk)
{
    constexpr int BM = 64, MT = 2;
    constexpr int BN = 2 * NT * 16;
    constexpr int BSEG = BN / 64;
    __shared__ __align__(16) _Float16 Ah[2][BM][LDK];
    __shared__ __align__(16) _Float16 Bh[2][BN][LDK];
    const int mBlk = M / BM;
    // XCD-sticky swizzle: n-blocks of one (b,m) A-tile share bid%8 -> same XCD L2
    const int bid = blockIdx.x;
    const int r = bid & 7, q = bid >> 3;
    const int ni = q % nBlk;
    const int mg = (q / nBlk) * 8 + r;
    const int b = mg / mBlk, m_idx = mg - b * mBlk;
    const int n0 = ni * BN, m0 = m_idx * BM;
    const int tid  = threadIdx.x;
    const int lane = tid & 63;
    const int w    = tid >> 6;
    const int wr   = w >> 1, wc = w & 1;
    const int lrow = lane & 15;
    const int loct = lane >> 4;

    f32x4 acc[MT][NT];
    #pragma unroll
    for (int i = 0; i < MT; ++i)
        #pragma unroll
        for (int j = 0; j < NT; ++j)
            acc[i][j] = (f32x4){0.f, 0.f, 0.f, 0.f};

    const int sOct = tid & 3, sRow = tid >> 2;   // A/B staging row + k-oct
    float va[8];
    uint4 pa, pb[BSEG];

    auto loadA = [&](int kk) {
        if (A_F32KM) {
            int m = tid & 63, ks = tid >> 6;      // 4 k-slices of 8
            #pragma unroll
            for (int j = 0; j < 8; ++j) {
                int kg = kk + ks * 8 + j;
                const float* Ap; int kl;
                if (kg < kSplit) { Ap = Af0; kl = kg; } else { Ap = Af1; kl = kg - kSplit; }
                va[j] = Ap[(long)b * strideAb + (long)kl * M + m0 + m];
            }
        } else {
            pa = *(const uint4*)(Ah_g + (long)b * strideAb +
                                 (long)(m0 + sRow) * K + kk + sOct * 8);
        }
    };
    auto loadB = [&](int kk) {
        #pragma unroll
        for (int p = 0; p < BSEG; ++p) {
            int ng = n0 + sRow + p * 64;
            if (EPI == HEPI_D34 && ng >= N)
                pb[p] = make_uint4(0, 0, 0, 0);
            else
                pb[p] = *(const uint4*)(Bh_g + (long)ng * K + kk + sOct * 8);
        }
    };
    auto storeAB = [&](int buf) {
        if (A_F32KM) {
            int m = tid & 63, ks = tid >> 6;
            uint4 h;
            h.x = pk2h(va[0], va[1]);
            h.y = pk2h(va[2], va[3]);
            h.z = pk2h(va[4], va[5]);
            h.w = pk2h(va[6], va[7]);
            *(uint4*)&Ah[buf][m][ks * 8] = h;
        } else {
            *(uint4*)&Ah[buf][sRow][sOct * 8] = pa;
        }
        #pragma unroll
        for (int p = 0; p < BSEG; ++p)
            *(uint4*)&Bh[buf][sRow + p * 64][sOct * 8] = pb[p];
    };

    loadA(0); loadB(0);
    storeAB(0);
    __syncthreads();
    int cur = 0;
    for (int kk = 0; kk < K; kk += 32) {
        const bool more = (kk + 32 < K);
        if (more) { loadA(kk + 32); loadB(kk + 32); }   // in flight during MFMA
        f16x8 bh[NT];
        #pragma unroll
        for (int nt = 0; nt < NT; ++nt)
            bh[nt] = *(const f16x8*)&Bh[cur][wc*NT*16 + nt*16 + lrow][loct*8];
        #pragma unroll
        for (int mt = 0; mt < MT; ++mt) {
            f16x8 ah = *(const f16x8*)&Ah[cur][wr*MT*16 + mt*16 + lrow][loct*8];
            #pragma unroll
            for (int nt = 0; nt < NT; ++nt)
                acc[mt][nt] = __builtin_amdgcn_mfma_f32_16x16x32_f16(ah, bh[nt], acc[mt][nt], 0, 0, 0);
        }
        if (more) {
            storeAB(cur ^ 1);
            __syncthreads();        // ONE barrier per k-iter
            cur ^= 1;
        }
    }
    // epilogue: C/D col=lane&15, row=(lane>>4)*4+reg
    #pragma unroll
    for (int mt = 0; mt < MT; ++mt) {
        #pragma unroll
        for (int r4 = 0; r4 < 4; ++r4) {
            int m = m0 + wr*MT*16 + mt * 16 + loct * 4 + r4;
            long rowb = (long)b * M + m;
            #pragma unroll
            for (int nt = 0; nt < NT; ++nt) {
                int n = n0 + wc*NT*16 + nt * 16 + lrow;
                float v = acc[mt][nt][r4];
                if (EPI == HEPI_XP) {
                    Oh0[rowb * N + n] = __float2half(v + bias[n]);
                } else if (EPI == HEPI_UZ) {
                    if (n < DIN) Oh0[rowb * DIN + n] = __float2half(v);
                    else         Oh1[rowb * DIN + (n - DIN)] = __float2half(v);
                } else if (EPI == HEPI_D34) {
                    if (n < DIN)            O0[rowb * DIN + n] = softplus_fast(v + bias[n]);
                    else if (n < DIN + 16)  Ob[rowb * 16 + (n - DIN)] = v;
                    else if (n < DIN + 32)  Oc[rowb * 16 + (n - DIN - 16)] = v;
                } else {
                    O0[rowb * N + n] = v;
                }
            }
        }
    }
}

// ---------------- merged weight prep: all weights -> fp16 (Wcomb fused product) ----
#define SZ_WP  131072
#define SZ_WIN 262144
#define SZ_WO  131072
#define SZ_WC  278528
__global__ __launch_bounds__(256)
void pack_all(const float* __restrict__ Wp, const float* __restrict__ Win,
              const float* __restrict__ Wout, const float* __restrict__ Wdt,
              const float* __restrict__ Wx,
              __half* __restrict__ wph, __half* __restrict__ winh,
              __half* __restrict__ woh, __half* __restrict__ wch)
{
    int i = blockIdx.x * 256 + threadIdx.x;
    if (i < SZ_WP) { wph[i] = __float2half(Wp[i]); return; }
    i -= SZ_WP;
    if (i < SZ_WIN) { winh[i] = __float2half(Win[i]); return; }
    i -= SZ_WIN;
    if (i < SZ_WO) { woh[i] = __float2half(Wout[i]); return; }
    i -= SZ_WO;
    if (i < SZ_WC) {
        int n = i >> 9, k = i & 511;
        float acc;
        if (n < DIN) {
            acc = 0.f;
            #pragma unroll
            for (int rr = 0; rr < DTR; ++rr)
                acc += Wdt[n * DTR + rr] * Wx[rr * DIN + k];
        } else {
            acc = Wx[(DTR + (n - DIN)) * DIN + k];
        }
        wch[i] = __float2half(acc);
    }
}

// ---------------- depthwise causal conv (k=4) + silu: fp16 in -> fp16 out ---------
__global__ __launch_bounds__(256)
void conv_silu_kernel(const __half* __restrict__ u_pre, const float* __restrict__ cw,
                      const float* __restrict__ cb, __half* __restrict__ u)
{
    long idx = (long)blockIdx.x * blockDim.x + threadIdx.x;
    int d = (int)(idx % DIN);
    long bl = idx / DIN;
    int l = (int)(bl % L);
    long brow = bl - l;
    float v = cb[d];
    #pragma unroll
    for (int j = 0; j < 4; ++j) {
        int li = l - 3 + j;
        if (li >= 0) v += __half2float(u_pre[(brow + li) * DIN + d]) * cw[d * 4 + j];
    }
    u[idx] = __float2half(silu_f(v));
}

// ---------------- chunked parallel selective scan, d-per-lane ----------------
#define NC 128
#define LC (L / NC)

__global__ __launch_bounds__(256)
void scan_phase1(const float* __restrict__ delta, const __half* __restrict__ u,
                 const float* __restrict__ Bm, const float* __restrict__ A_log,
                 float* __restrict__ Asum, float* __restrict__ Xsum)
{
    __shared__ float sB[LC][DSTATE];
    const int gd = blockIdx.x & 1;
    const int c  = (blockIdx.x >> 1) & (NC - 1);
    const int b  = blockIdx.x >> 8;
    const int d  = gd * 256 + threadIdx.x;
    const int t0 = c * LC;
    float Arow[DSTATE];
    #pragma unroll
    for (int q = 0; q < 4; ++q) {
        float4 v = *(const float4*)&A_log[d * DSTATE + q * 4];
        Arow[q * 4 + 0] = -__expf(v.x);
        Arow[q * 4 + 1] = -__expf(v.y);
        Arow[q * 4 + 2] = -__expf(v.z);
        Arow[q * 4 + 3] = -__expf(v.w);
    }
    for (int i = threadIdx.x; i < LC * DSTATE; i += 256)
        sB[i >> 4][i & 15] = Bm[((long)b * L + t0 + (i >> 4)) * DSTATE + (i & 15)];
    __syncthreads();
    float P[DSTATE], X[DSTATE];
    #pragma unroll
    for (int s = 0; s < DSTATE; ++s) { P[s] = 1.f; X[s] = 0.f; }
    for (int t = 0; t < LC; ++t) {
        long gidx = ((long)b * L + t0 + t) * DIN + d;
        float dlt = delta[gidx];
        float du  = dlt * __half2float(u[gidx]);
        #pragma unroll
        for (int s = 0; s < DSTATE; ++s) {
            float a = __expf(dlt * Arow[s]);
            P[s] *= a;
            X[s] = a * X[s] + du * sB[t][s];
        }
    }
    long o = (((long)b * NC + c) * DIN + d) * DSTATE;
    #pragma unroll
    for (int q = 0; q < 4; ++q) {
        *(float4*)&Asum[o + q * 4] = make_float4(P[q*4], P[q*4+1], P[q*4+2], P[q*4+3]);
        *(float4*)&Xsum[o + q * 4] = make_float4(X[q*4], X[q*4+1], X[q*4+2], X[q*4+3]);
    }
}

__global__ __launch_bounds__(256)
void scan_phase2(const float* __restrict__ Asum, float* __restrict__ Xsum)
{
    int lane = blockIdx.x * 256 + threadIdx.x;
    int b = lane / (DIN * DSTATE);
    int rem = lane % (DIN * DSTATE);
    float h = 0.f;
    for (int c = 0; c < NC; ++c) {
        long idx = ((long)b * NC + c) * (DIN * DSTATE) + rem;
        float A = Asum[idx], X = Xsum[idx];
        Xsum[idx] = h;
        h = A * h + X;
    }
}

__global__ __launch_bounds__(256)
void scan_phase3(const float* __restrict__ delta, const __half* __restrict__ u,
                 const float* __restrict__ Bm, const float* __restrict__ Cm,
                 const __half* __restrict__ z, const float* __restrict__ A_log,
                 const float* __restrict__ Dp, const float* __restrict__ Hinit,
                 __half* __restrict__ y2h)
{
    __shared__ float sB[LC][DSTATE], sC[LC][DSTATE];
    const int gd = blockIdx.x & 1;
    const int c  = (blockIdx.x >> 1) & (NC - 1);
    const int b  = blockIdx.x >> 8;
    const int d  = gd * 256 + threadIdx.x;
    const int t0 = c * LC;
    float Arow[DSTATE];
    #pragma unroll
    for (int q = 0; q < 4; ++q) {
        float4 v = *(const float4*)&A_log[d * DSTATE + q * 4];
        Arow[q * 4 + 0] = -__expf(v.x);
        Arow[q * 4 + 1] = -__expf(v.y);
        Arow[q * 4 + 2] = -__expf(v.z);
        Arow[q * 4 + 3] = -__expf(v.w);
    }
    for (int i = threadIdx.x; i < LC * DSTATE; i += 256) {
        long gidx = ((long)b * L + t0 + (i >> 4)) * DSTATE + (i & 15);
        sB[i >> 4][i & 15] = Bm[gidx];
        sC[i >> 4][i & 15] = Cm[gidx];
    }
    float h[DSTATE];
    {
        long o = (((long)b * NC + c) * DIN + d) * DSTATE;
        #pragma unroll
        for (int q = 0; q < 4; ++q) {
            float4 v = *(const float4*)&Hinit[o + q * 4];
            h[q * 4 + 0] = v.x; h[q * 4 + 1] = v.y;
            h[q * 4 + 2] = v.z; h[q * 4 + 3] = v.w;
        }
    }
    const float Dval = Dp[d];
    __syncthreads();
    for (int t = 0; t < LC; ++t) {
        long gidx = ((long)b * L + t0 + t) * DIN + d;
        float dlt = delta[gidx];
        float uu  = __half2float(u[gidx]);
        float zz  = __half2float(z[gidx]);
        float du  = dlt * uu;
        float y = 0.f;
        #pragma unroll
        for (int s = 0; s < DSTATE; ++s) {
            float a = __expf(dlt * Arow[s]);
            h[s] = h[s] * a + du * sB[t][s];
            y += h[s] * sC[t][s];
        }
        y2h[gidx] = __float2half((y + uu * Dval) * silu_f(zz));
    }
}

// ---------------- LayerNorm over C + transpose to (B,C,L) ----------------
__global__ __launch_bounds__(256)
void ln_kernel(const float* __restrict__ X, const float* __restrict__ gamma,
               const float* __restrict__ beta, float* __restrict__ out)
{
    __shared__ float tile[32][257];
    __shared__ float sMu[32], sRs[32];
    const int l0 = blockIdx.x * 32;
    const int b  = blockIdx.y;
    const int tid = threadIdx.x;
    for (int i = tid; i < 32 * 256; i += 256) {
        int l = i >> 8, c = i & 255;
        tile[l][c] = X[((long)b * L + l0 + l) * CDIM + c];
    }
    __syncthreads();
    {
        int l = tid >> 3, sub = tid & 7;
        float s1 = 0.f, s2 = 0.f;
        for (int c = sub * 32; c < sub * 32 + 32; ++c) {
            float v = tile[l][c];
            s1 += v; s2 += v * v;
        }
        s1 += __shfl_xor(s1, 1); s2 += __shfl_xor(s2, 1);
        s1 += __shfl_xor(s1, 2); s2 += __shfl_xor(s2, 2);
        s1 += __shfl_xor(s1, 4); s2 += __shfl_xor(s2, 4);
        if (sub == 0) {
            float mu = s1 * (1.f / 256.f);
            float var = s2 * (1.f / 256.f) - mu * mu;
            sMu[l] = mu;
            sRs[l] = rsqrtf(var + 1e-5f);
        }
    }
    __syncthreads();
    for (int i = tid; i < 32 * 256; i += 256) {
        int ll = i & 31, c = i >> 5;
        float v = (tile[ll][c] - sMu[ll]) * sRs[ll] * gamma[c] + beta[c];
        out[((long)b * CDIM + c) * L + l0 + ll] = v;
    }
}

extern "C" void kernel_launch(void* const* d_in, const int* in_sizes, int n_in,
                              void* d_out, int out_size, void* d_ws, size_t ws_size,
                              hipStream_t stream)
{
    const float* sp   = (const float*)d_in[0];
    const float* fq   = (const float*)d_in[1];
    const float* Wp   = (const float*)d_in[2];
    const float* bp   = (const float*)d_in[3];
    const float* Win  = (const float*)d_in[4];
    const float* cw   = (const float*)d_in[5];
    const float* cb   = (const float*)d_in[6];
    const float* Wx   = (const float*)d_in[7];
    const float* Wdt  = (const float*)d_in[8];
    const float* bdt  = (const float*)d_in[9];
    const float* Alog = (const float*)d_in[10];
    const float* Dp   = (const float*)d_in[11];
    const float* Wout = (const float*)d_in[12];
    const float* gam  = (const float*)d_in[13];
    const float* bet  = (const float*)d_in[14];
    float* out = (float*)d_out;
    float* ws  = (float*)d_ws;

    const size_t NLD = (size_t)BATCH * L * DIN;   // 8.39M
    const size_t NLC = (size_t)BATCH * L * CDIM;  // 4.19M

    size_t off = 0;
    float*  delta = ws + off; off += NLD;                 // fp32 delta
    __half* u16   = (__half*)(ws + off); off += NLD / 2;  // pre-conv u
    __half* u16c  = (__half*)(ws + off); off += NLD / 2;  // post-conv silu(u)
    __half* z16   = (__half*)(ws + off); off += NLD / 2;
    __half* y16   = (__half*)(ws + off); off += NLD / 2;
    __half* xp16  = (__half*)(ws + off); off += NLC / 2;
    float*  xmix  = ws + off; off += NLC;
    __half* wph   = (__half*)(ws + off); off += SZ_WP / 2;
    __half* winh  = (__half*)(ws + off); off += SZ_WIN / 2;
    __half* woh   = (__half*)(ws + off); off += SZ_WO / 2;
    __half* wch   = (__half*)(ws + off); off += SZ_WC / 2;
    float*  Bmb   = ws + off; off += (size_t)BATCH * L * DSTATE;
    float*  Cmb   = ws + off; off += (size_t)BATCH * L * DSTATE;
    float*  Asum  = ws + off; off += (size_t)BATCH * NC * DIN * DSTATE;
    float*  Xsum  = ws + off; off += (size_t)BATCH * NC * DIN * DSTATE;

    dim3 blk(256);
    pack_all<<<dim3((SZ_WP + SZ_WIN + SZ_WO + SZ_WC) / 256), blk, 0, stream>>>(
        Wp, Win, Wout, Wdt, Wx, wph, winh, woh, wch);

    // GEMM1 (fp16): x_proj = x_cat @ Wp^T + bp  (A fp32 K-major; BM=64, NT=2, nBlk=4)
    hgemm<HEPI_XP, true, 2><<<dim3(BATCH * (L/64) * 4), blk, 0, stream>>>(
        sp, fq, nullptr, wph, bp, nullptr, xp16, nullptr, nullptr, nullptr,
        L, CDIM, 2 * CDIM, CDIM, (long)CDIM * L, 4);
    // GEMM2 (fp16): xz = x_proj @ Win^T -> u16 / z16  (BM=64, NT=4, nBlk=8)
    hgemm<HEPI_UZ, false, 4><<<dim3(BATCH * (L/64) * 8), blk, 0, stream>>>(
        nullptr, nullptr, xp16, winh, nullptr, nullptr, u16, z16, nullptr, nullptr,
        L, 2 * DIN, CDIM, 1 << 30, (long)L * CDIM, 8);
    conv_silu_kernel<<<dim3((int)(NLD / 256)), blk, 0, stream>>>(u16, cw, cb, u16c);
    // D34 (fp16): [delta | Bm | Cm] = u @ Wcomb^T  (BM=64, NT=4, nBlk=5)
    hgemm<HEPI_D34, false, 4><<<dim3(BATCH * (L/64) * 5), blk, 0, stream>>>(
        nullptr, nullptr, u16c, wch, bdt, delta, nullptr, nullptr, Bmb, Cmb,
        L, 544, DIN, 1 << 30, (long)L * DIN, 5);

    scan_phase1<<<dim3(BATCH * NC * 2), blk, 0, stream>>>(delta, u16c, Bmb, Alog, Asum, Xsum);
    scan_phase2<<<dim3(BATCH * DIN * DSTATE / 256), blk, 0, stream>>>(Asum, Xsum);
    scan_phase3<<<dim3(BATCH * NC * 2), blk, 0, stream>>>(
        delta, u16c, Bmb, Cmb, z16, Alog, Dp, Xsum, y16);

    // GEMM5 (fp16): x_mixed = y2 @ Wout^T  (BM=64, NT=2, nBlk=4)
    hgemm<HEPI_F32, false, 2><<<dim3(BATCH * (L/64) * 4), blk, 0, stream>>>(
        nullptr, nullptr, y16, woh, nullptr, xmix, nullptr, nullptr, nullptr, nullptr,
        L, CDIM, DIN, 1 << 30, (long)L * DIN, 4);
    ln_kernel<<<dim3(L / 32, BATCH), blk, 0, stream>>>(xmix, gam, bet, out);
}